// Round 9
// baseline (114.134 us; speedup 1.0000x reference)
//
#include <hip/hip_runtime.h>
#include <stdint.h>
#include <math.h>

#define B_DIM 4096
#define H_DIM 1024
#define NI_DIM 4096
#define NQ_DIM 2048
#define K_DIM 5120   // H + NI
#define NKT 160      // K_DIM / 32

typedef __attribute__((ext_vector_type(8))) short short8;
typedef __attribute__((ext_vector_type(4))) float f32x4;

__device__ __forceinline__ unsigned short f2bf(float f) {
  unsigned u = __float_as_uint(f);
  u += 0x7FFFu + ((u >> 16) & 1u);  // round-to-nearest-even
  return (unsigned short)(u >> 16);
}
__device__ __forceinline__ float bf2f(unsigned short s) {
  return __uint_as_float(((unsigned)s) << 16);
}
__device__ __forceinline__ unsigned pkbf(float a, float b) {
  unsigned r;
  asm("v_cvt_pk_bf16_f32 %0, %1, %2" : "=v"(r) : "v"(a), "v"(b));
  return r;
}

__device__ __forceinline__ void gload_lds16(const void* g, void* l) {
  __builtin_amdgcn_global_load_lds(
      (__attribute__((address_space(1))) void*)(uintptr_t)g,
      (__attribute__((address_space(3))) void*)l, 16, 0, 0);
}

// fp32 -> bf16 cast into staged-tile layout, LDS-free linear-write version.
// Staged chunk16 index = ((rt*NKT+kt)*4 + s)*128 + r decomposes linearly:
// r=c&127, s=(c>>7)&3, kt=(c>>9)%NKT, rt=(c>>9)/NKT -- so thread owning
// linear chunk c writes 16B at dst+c*16 (perfect coalescing, no bounce).
// Read: matching 32B fp32 segment; per-lane row-strided, 64B lines fully
// consumed by adjacent waves via L1/L2 (and L3-warm across replays).
__global__ __launch_bounds__(256) void cast_v5(
    const float* __restrict__ X0, const float* __restrict__ X1,
    const float* __restrict__ W0, const float* __restrict__ W1,
    short* __restrict__ Xc, short* __restrict__ Wc) {
  const long long XCH = (long long)(B_DIM / 128) * NKT * 512;  // X chunks
  const long long TOT = XCH + (long long)(H_DIM / 128) * NKT * 512;
  const long long stride = (long long)gridDim.x * 256;
  for (long long c = (long long)blockIdx.x * 256 + threadIdx.x; c < TOT;
       c += stride) {
    bool isX = c < XCH;
    long long cc = isX ? c : c - XCH;
    int r = (int)(cc & 127);
    int s = (int)((cc >> 7) & 3);
    long long t9 = cc >> 9;           // rt*NKT + kt
    int kt = (int)(t9 % NKT);
    int rt = (int)(t9 / NKT);
    int grow = rt * 128 + r;
    int gcol = kt * 32 + s * 8;
    const float* src;
    int cols;
    if (kt < 32) { src = isX ? X0 : W0; cols = 1024; }
    else         { src = isX ? X1 : W1; cols = 4096; gcol -= 1024; }
    const float* p = src + (long long)grow * cols + gcol;
    float4 a = *(const float4*)(p);
    float4 b = *(const float4*)(p + 4);
    uint4 o;
    o.x = pkbf(a.x, a.y); o.y = pkbf(a.z, a.w);
    o.z = pkbf(b.x, b.y); o.w = pkbf(b.z, b.w);
    short* dst = isX ? (Xc + cc * 8) : (Wc + cc * 8);
    *(uint4*)dst = o;
  }
}

// LDS byte-swizzle for the epilogue transpose buffer [col][row] bf16.
__device__ __forceinline__ int ep_swz(int col, int rw) {
  int byte = col * 256 + rw * 2;
  byte ^= ((col ^ (col >> 3)) & 7) << 4;   // spread banks, keeps 8B align
  return byte;
}

// Split-K GEMM (proven: 46.5us, MfmaUtil 39%, conflicts epilogue-only).
// 128x128 tile, BK=32, 4 waves (2x2), dbuf LDS via global_load_lds w=16 on
// staged-tile Xc/Wc; bf16 partials via LDS-transposed coalesced epilogue.
__global__ __launch_bounds__(256, 4) void gemm_splitk(
    const short* __restrict__ Xc, const short* __restrict__ Wc,
    short* __restrict__ P, int ntk) {
  __shared__ __align__(16) short SH[16384];  // A dbuf 16KB | B dbuf 16KB
  const int tid = threadIdx.x;
  const int lane = tid & 63;
  const int wid = tid >> 6;
  const int wm = wid >> 1, wn = wid & 1;
  const int fr = lane & 15, fq = lane >> 4;

  const int nwg = gridDim.x;
  const int orig = blockIdx.x;
  const int cpx = nwg >> 3;
  const int swz = (orig & 7) * cpx + (orig >> 3);
  const int bz = swz >> 8;
  const int bm = (swz >> 3) & 31;
  const int bn = swz & 7;
  const int kt0 = bz * ntk;

  const int c0 = tid, c1 = tid + 256;
  const short* gA = Xc + (((long long)bm * NKT + kt0) << 12);  // *4096 shorts
  const short* gB = Wc + (((long long)bn * NKT + kt0) << 12);

  f32x4 acc[4][4] = {};

  gload_lds16(gA + c0 * 8, &SH[c0 * 8]);
  gload_lds16(gA + c1 * 8, &SH[c1 * 8]);
  gload_lds16(gB + c0 * 8, &SH[8192 + c0 * 8]);
  gload_lds16(gB + c1 * 8, &SH[8192 + c1 * 8]);
  __syncthreads();

  int cur = 0;
  for (int t = 0; t < ntk; ++t) {
    if (t + 1 < ntk) {
      const short* nA = gA + (long long)(t + 1) * 4096;
      const short* nB = gB + (long long)(t + 1) * 4096;
      short* lA = &SH[(cur ^ 1) * 4096];
      short* lB = &SH[8192 + (cur ^ 1) * 4096];
      gload_lds16(nA + c0 * 8, lA + c0 * 8);
      gload_lds16(nA + c1 * 8, lA + c1 * 8);
      gload_lds16(nB + c0 * 8, lB + c0 * 8);
      gload_lds16(nB + c1 * 8, lB + c1 * 8);
    }
    const short* a_base = &SH[cur * 4096];
    const short* b_base = &SH[8192 + cur * 4096];
    short8 av[4], bv[4];
#pragma unroll
    for (int i = 0; i < 4; i++) {
      // [slot=fq][row = w*64 + i*16 + fr][8] -> conflict-free granules
      av[i] = *(const short8*)(a_base + (fq * 128 + wm * 64 + i * 16 + fr) * 8);
      bv[i] = *(const short8*)(b_base + (fq * 128 + wn * 64 + i * 16 + fr) * 8);
    }
#pragma unroll
    for (int mi = 0; mi < 4; mi++)
#pragma unroll
      for (int ni = 0; ni < 4; ni++)
        acc[mi][ni] = __builtin_amdgcn_mfma_f32_16x16x32_bf16(
            av[mi], bv[ni], acc[mi][ni], 0, 0, 0);
    __syncthreads();
    cur ^= 1;
  }

  // ---- epilogue: bf16 transpose through LDS, coalesced global stores ----
#pragma unroll
  for (int ni = 0; ni < 4; ni++) {
    int col = wn * 64 + ni * 16 + fr;
#pragma unroll
    for (int mi = 0; mi < 4; mi++) {
      int rw = wm * 64 + mi * 16 + fq * 4;
      unsigned lo = (unsigned)f2bf(acc[mi][ni][0]) |
                    ((unsigned)f2bf(acc[mi][ni][1]) << 16);
      unsigned hi = (unsigned)f2bf(acc[mi][ni][2]) |
                    ((unsigned)f2bf(acc[mi][ni][3]) << 16);
      uint2 pk; pk.x = lo; pk.y = hi;
      *(uint2*)((char*)SH + ep_swz(col, rw)) = pk;
    }
  }
  __syncthreads();
  short* Pp = P + (long long)bz * B_DIM * H_DIM;
#pragma unroll
  for (int h = 0; h < 8; ++h) {
    int chunk = tid + h * 256;        // 2048 chunks = 128 rows x 16 colblocks
    int rr = chunk >> 4;
    int j = chunk & 15;
    short8 o;
#pragma unroll
    for (int k = 0; k < 8; ++k) {
      o[k] = *(const short*)((char*)SH + ep_swz(j * 8 + k, rr));
    }
    *(short8*)(Pp + (long long)(bm * 128 + rr) * H_DIM + bn * 128 + j * 8) = o;
  }
}

// Fused: per-row split-K reduce + bias + tanh + hidden write + one-hot
// select + Wy dot + sigmoid + BCE term.
__global__ __launch_bounds__(256) void fuse_row(
    const short* __restrict__ P, const float* __restrict__ bt,
    const float* __restrict__ bx, const float* __restrict__ Y,
    const float* __restrict__ truth, const float* __restrict__ Wy,
    const float* __restrict__ by, float* __restrict__ predOut,
    float* __restrict__ hidden, float* __restrict__ bce, int S) {
  const int b = blockIdx.x;
  const int tid = threadIdx.x;
  __shared__ int s_cnt;
  __shared__ int s_idx[8];
  __shared__ float s_val[8];
  __shared__ float s_red[4];
  if (tid == 0) s_cnt = 0;

  const int c = tid * 4;
  float s0 = 0.f, s1 = 0.f, s2 = 0.f, s3 = 0.f;
  for (int z = 0; z < S; ++z) {
    const short* Pr = P + ((long long)z * B_DIM + b) * H_DIM + c;
    uint2 u = *(const uint2*)Pr;
    s0 += bf2f((unsigned short)(u.x & 0xffff));
    s1 += bf2f((unsigned short)(u.x >> 16));
    s2 += bf2f((unsigned short)(u.y & 0xffff));
    s3 += bf2f((unsigned short)(u.y >> 16));
  }
  float4 bt4 = *(const float4*)(bt + c);
  float4 bx4 = *(const float4*)(bx + c);
  float h0 = tanhf(s0 + bt4.x + bx4.x);
  float h1 = tanhf(s1 + bt4.y + bx4.y);
  float h2 = tanhf(s2 + bt4.z + bx4.z);
  float h3 = tanhf(s3 + bt4.w + bx4.w);
  float* Hr = hidden + (long long)b * H_DIM + c;  // base unaligned -> scalar
  Hr[0] = h0; Hr[1] = h1; Hr[2] = h2; Hr[3] = h3;

  __syncthreads();  // covers s_cnt init
  const float4* Yr = (const float4*)(Y + (long long)b * NQ_DIM);
#pragma unroll
  for (int hh = 0; hh < NQ_DIM / 4 / 256; ++hh) {
    int j = tid + hh * 256;
    float4 v = Yr[j];
    if (v.x != 0.0f) { int p = atomicAdd(&s_cnt, 1); if (p < 8) { s_idx[p] = 4 * j;     s_val[p] = v.x; } }
    if (v.y != 0.0f) { int p = atomicAdd(&s_cnt, 1); if (p < 8) { s_idx[p] = 4 * j + 1; s_val[p] = v.y; } }
    if (v.z != 0.0f) { int p = atomicAdd(&s_cnt, 1); if (p < 8) { s_idx[p] = 4 * j + 2; s_val[p] = v.z; } }
    if (v.w != 0.0f) { int p = atomicAdd(&s_cnt, 1); if (p < 8) { s_idx[p] = 4 * j + 3; s_val[p] = v.w; } }
  }
  __syncthreads();
  int cnt = s_cnt < 8 ? s_cnt : 8;
  float predv = 0.0f;
  for (int it = 0; it < cnt; ++it) {
    int q = s_idx[it];
    float4 w = *(const float4*)(Wy + (long long)q * H_DIM + c);
    float part = h0 * w.x + h1 * w.y + h2 * w.z + h3 * w.w;
#pragma unroll
    for (int off = 32; off > 0; off >>= 1) part += __shfl_down(part, off, 64);
    if ((tid & 63) == 0) s_red[tid >> 6] = part;
    __syncthreads();
    if (tid == 0) {
      float z = s_red[0] + s_red[1] + s_red[2] + s_red[3] + by[q];
      float p = 1.0f / (1.0f + expf(-z));
      predv += s_val[it] * p;
    }
    __syncthreads();
  }
  if (tid == 0) {
    predOut[b] = predv;
    float t = truth[b];
    float lp = fmaxf(logf(predv), -100.0f);
    float l1p = fmaxf(log1pf(-predv), -100.0f);
    bce[b] = -(t * lp + (1.0f - t) * l1p);
  }
}

__global__ __launch_bounds__(256) void reduce_err(
    const float* __restrict__ bce, float* __restrict__ errOut) {
  float s = 0.0f;
  for (int i = threadIdx.x; i < B_DIM; i += 256) s += bce[i];
#pragma unroll
  for (int off = 32; off > 0; off >>= 1) s += __shfl_down(s, off, 64);
  __shared__ float red[4];
  if ((threadIdx.x & 63) == 0) red[threadIdx.x >> 6] = s;
  __syncthreads();
  if (threadIdx.x == 0) errOut[0] = red[0] + red[1] + red[2] + red[3];
}

extern "C" void kernel_launch(void* const* d_in, const int* in_sizes, int n_in,
                              void* d_out, int out_size, void* d_ws, size_t ws_size,
                              hipStream_t stream) {
  (void)in_sizes; (void)n_in; (void)out_size;
  const float* state  = (const float*)d_in[0];
  const float* inputX = (const float*)d_in[1];
  const float* inputY = (const float*)d_in[2];
  const float* truth  = (const float*)d_in[3];
  const float* W_t    = (const float*)d_in[4];
  const float* b_t    = (const float*)d_in[5];
  const float* W_x    = (const float*)d_in[6];
  const float* b_x    = (const float*)d_in[7];
  const float* W_y    = (const float*)d_in[8];
  const float* b_y    = (const float*)d_in[9];

  const size_t XC_B = (size_t)B_DIM * K_DIM * 2;   // 41.9 MB
  const size_t WC_B = (size_t)H_DIM * K_DIM * 2;   // 10.5 MB
  const size_t PART = (size_t)B_DIM * H_DIM * 2;   // 8.4 MB per split (bf16)

  int S = 1;
  if (ws_size >= XC_B + WC_B + 4 * PART + 16384) S = 4;
  else if (ws_size >= XC_B + WC_B + 2 * PART + 16384) S = 2;

  short* Xc = (short*)d_ws;
  short* Wc = (short*)((char*)d_ws + XC_B);
  short* P  = (short*)((char*)d_ws + XC_B + WC_B);
  float* bce = (float*)((char*)d_ws + XC_B + WC_B + (size_t)S * PART);

  float* predOut = (float*)d_out;             // [0 .. 4095]
  float* errOut  = predOut + B_DIM;           // [4096]
  float* hidden  = predOut + B_DIM + 1;       // [4097 ..]

  cast_v5<<<2048, 256, 0, stream>>>(state, inputX, W_t, W_x, Xc, Wc);

  gemm_splitk<<<256 * S, 256, 0, stream>>>(Xc, Wc, P, NKT / S);

  fuse_row<<<B_DIM, 256, 0, stream>>>(P, b_t, b_x, inputY, truth, W_y, b_y,
                                      predOut, hidden, bce, S);
  reduce_err<<<1, 256, 0, stream>>>(bce, errOut);
}

// Round 10
// 111.244 us; speedup vs baseline: 1.0260x; 1.0260x over previous
//
#include <hip/hip_runtime.h>
#include <hip/hip_bf16.h>
#include <stdint.h>
#include <math.h>

#define B_DIM 4096
#define H_DIM 1024
#define NI_DIM 4096
#define NQ_DIM 2048
#define K_DIM 5120   // H + NI
#define NKT 160      // K_DIM / 32

typedef __attribute__((ext_vector_type(8))) short short8;
typedef __attribute__((ext_vector_type(4))) float f32x4;

__device__ __forceinline__ unsigned short f2bf(float f) {
  unsigned u = __float_as_uint(f);
  u += 0x7FFFu + ((u >> 16) & 1u);  // round-to-nearest-even
  return (unsigned short)(u >> 16);
}
__device__ __forceinline__ float bf2f(unsigned short s) {
  return __uint_as_float(((unsigned)s) << 16);
}

__device__ __forceinline__ void gload_lds16(const void* g, void* l) {
  __builtin_amdgcn_global_load_lds(
      (__attribute__((address_space(1))) void*)(uintptr_t)g,
      (__attribute__((address_space(3))) void*)l, 16, 0, 0);
}

// fp32 -> bf16 cast into staged-tile layout, W only (1280 blocks, ~31.5MB).
//   dst chunk16 index = ((rowTile*NKT + kt)*4 + slot)*128 + row_in_tile
__global__ __launch_bounds__(256) void cast_w(
    const float* __restrict__ Wt, const float* __restrict__ Wx,
    short* __restrict__ Wc) {
  __shared__ __align__(16) short lds[4096];  // [4][128][8]
  const int bt = blockIdx.x;
  const int rowTile = bt / NKT;
  const int kt = bt % NKT;
  const float* src;
  long long srcBase;
  int cols;
  if (kt < 32) { src = Wt; cols = 1024; srcBase = (long long)kt * 32; }
  else         { src = Wx; cols = 4096; srcBase = (long long)(kt - 32) * 32; }
  const int tid = threadIdx.x;
#pragma unroll
  for (int half = 0; half < 2; ++half) {
    int c = tid + half * 256;          // cell: row r = c>>2, slot s = c&3
    int r = c >> 2, s = c & 3;
    long long sa = ((long long)(rowTile * 128 + r)) * cols + srcBase + s * 8;
    float4 v0 = *(const float4*)(src + sa);
    float4 v1 = *(const float4*)(src + sa + 4);
    short8 o;
    o[0] = (short)f2bf(v0.x); o[1] = (short)f2bf(v0.y);
    o[2] = (short)f2bf(v0.z); o[3] = (short)f2bf(v0.w);
    o[4] = (short)f2bf(v1.x); o[5] = (short)f2bf(v1.y);
    o[6] = (short)f2bf(v1.z); o[7] = (short)f2bf(v1.w);
    *(short8*)(&lds[(s * 128 + r) * 8]) = o;
  }
  __syncthreads();
  short* dtile = Wc + (((long long)rowTile * NKT + kt) * 512) * 8;
#pragma unroll
  for (int half = 0; half < 2; ++half) {
    int c = tid + half * 256;
    *(short8*)(dtile + c * 8) = *(const short8*)(&lds[c * 8]);
  }
}

// LDS byte-swizzle for the epilogue transpose buffer [col][row] bf16.
__device__ __forceinline__ int ep_swz(int col, int rw) {
  int byte = col * 256 + rw * 2;
  byte ^= ((col ^ (col >> 3)) & 7) << 4;   // spread banks, keeps 8B align
  return byte;
}

// Split-K GEMM, A staged as fp32 DIRECTLY from state/inputX (no X-cast).
// A LDS: [row 0..127][8 phys qslots][4 f32] per buf (16KB), qp = q^(row&7)
// XOR-swizzle: linear LDS dest + inverse-swizzled GLOBAL source (8x128B
// contiguous row-segments per wave) + swizzled ds_read (8 lanes/bank
// uniform -> conflict-free). Convert fp32->bf16 with v_cvt_pk on consume.
// B path / MFMA core / epilogue unchanged from the proven kernel.
__global__ __launch_bounds__(256, 3) void gemm_f32a(
    const float* __restrict__ state, const float* __restrict__ inputX,
    const short* __restrict__ Wc, short* __restrict__ P, int ntk) {
  __shared__ __align__(16) short SH[24576];  // A f32 2x16KB | B bf16 2x8KB
  const int tid = threadIdx.x;
  const int lane = tid & 63;
  const int wid = tid >> 6;
  const int wm = wid >> 1, wn = wid & 1;
  const int fr = lane & 15, fq = lane >> 4;

  const int nwg = gridDim.x;                 // 1024, %8==0
  const int orig = blockIdx.x;
  const int cpx = nwg >> 3;
  const int swz = (orig & 7) * cpx + (orig >> 3);
  const int bz = swz >> 8;
  const int bm = (swz >> 3) & 31;
  const int bn = swz & 7;
  const int kt0 = bz * ntk;

  // B staging (proven path)
  const int c0 = tid, c1 = tid + 256;
  const short* gB = Wc + (((long long)bn * NKT + kt0) << 12);

  // A staging chunk params: chunk c -> row r=c>>3, phys slot qp=c&7,
  // logical q = qp ^ (r&7); global offset = grow*cols + ktcol + q*4
  long long aoffS[4], aoffX[4];
#pragma unroll
  for (int j = 0; j < 4; ++j) {
    int c = tid + j * 256;
    int r = c >> 3, qp = c & 7;
    int ql = qp ^ (r & 7);
    long long grow = bm * 128 + r;
    aoffS[j] = grow * 1024 + ql * 4;
    aoffX[j] = grow * 4096 + ql * 4;
  }

  f32x4 acc[4][4] = {};

  // prologue: stage A(0) (4 gloads) + B(0) (2 gloads) into buf 0
  {
    int ktg = kt0;
    const float* baseS = state + (long long)ktg * 32;
    const float* baseX = inputX + (long long)(ktg - 32) * 32;
#pragma unroll
    for (int j = 0; j < 4; ++j) {
      const float* g = (ktg < 32) ? (baseS + aoffS[j]) : (baseX + aoffX[j]);
      gload_lds16(g, &SH[(tid + j * 256) * 8]);
    }
    gload_lds16(gB + c0 * 8, &SH[16384 + c0 * 8]);
    gload_lds16(gB + c1 * 8, &SH[16384 + c1 * 8]);
  }
  __syncthreads();

  int cur = 0;
  for (int t = 0; t < ntk; ++t) {
    if (t + 1 < ntk) {
      int ktg = kt0 + t + 1;
      const float* baseS = state + (long long)ktg * 32;
      const float* baseX = inputX + (long long)(ktg - 32) * 32;
      short* lA = &SH[(cur ^ 1) * 8192];
#pragma unroll
      for (int j = 0; j < 4; ++j) {
        const float* g = (ktg < 32) ? (baseS + aoffS[j]) : (baseX + aoffX[j]);
        gload_lds16(g, lA + (tid + j * 256) * 8);
      }
      const short* nB = gB + (long long)(t + 1) * 4096;
      short* lB = &SH[16384 + (cur ^ 1) * 4096];
      gload_lds16(nB + c0 * 8, lB + c0 * 8);
      gload_lds16(nB + c1 * 8, lB + c1 * 8);
    }
    const float4* a_base = (const float4*)&SH[cur * 8192];
    const short* b_base = &SH[16384 + cur * 4096];
    short8 av[4], bv[4];
#pragma unroll
    for (int i = 0; i < 4; i++) {
      int row = wm * 64 + i * 16 + fr;
      int e = row & 7;
      float4 lo = a_base[row * 8 + ((2 * fq) ^ e)];
      float4 hi = a_base[row * 8 + ((2 * fq + 1) ^ e)];
      union { short8 s; __hip_bfloat162 h[4]; } u;
      u.h[0] = __float22bfloat162_rn(make_float2(lo.x, lo.y));
      u.h[1] = __float22bfloat162_rn(make_float2(lo.z, lo.w));
      u.h[2] = __float22bfloat162_rn(make_float2(hi.x, hi.y));
      u.h[3] = __float22bfloat162_rn(make_float2(hi.z, hi.w));
      av[i] = u.s;
      // B: [slot=fq][row = wn*64 + i*16 + fr][8] -> conflict-free granules
      bv[i] = *(const short8*)(b_base + (fq * 128 + wn * 64 + i * 16 + fr) * 8);
    }
#pragma unroll
    for (int mi = 0; mi < 4; mi++)
#pragma unroll
      for (int ni = 0; ni < 4; ni++)
        acc[mi][ni] = __builtin_amdgcn_mfma_f32_16x16x32_bf16(
            av[mi], bv[ni], acc[mi][ni], 0, 0, 0);
    __syncthreads();
    cur ^= 1;
  }

  // ---- epilogue: bf16 transpose through LDS, coalesced global stores ----
#pragma unroll
  for (int ni = 0; ni < 4; ni++) {
    int col = wn * 64 + ni * 16 + fr;
#pragma unroll
    for (int mi = 0; mi < 4; mi++) {
      int rw = wm * 64 + mi * 16 + fq * 4;
      unsigned lo = (unsigned)f2bf(acc[mi][ni][0]) |
                    ((unsigned)f2bf(acc[mi][ni][1]) << 16);
      unsigned hi = (unsigned)f2bf(acc[mi][ni][2]) |
                    ((unsigned)f2bf(acc[mi][ni][3]) << 16);
      uint2 pk; pk.x = lo; pk.y = hi;
      *(uint2*)((char*)SH + ep_swz(col, rw)) = pk;
    }
  }
  __syncthreads();
  short* Pp = P + (long long)bz * B_DIM * H_DIM;
#pragma unroll
  for (int h = 0; h < 8; ++h) {
    int chunk = tid + h * 256;        // 2048 chunks = 128 rows x 16 colblocks
    int rr = chunk >> 4;
    int j = chunk & 15;
    short8 o;
#pragma unroll
    for (int k = 0; k < 8; ++k) {
      o[k] = *(const short*)((char*)SH + ep_swz(j * 8 + k, rr));
    }
    *(short8*)(Pp + (long long)(bm * 128 + rr) * H_DIM + bn * 128 + j * 8) = o;
  }
}

// Fused: per-row split-K reduce + bias + tanh + hidden write + one-hot
// select + Wy dot + sigmoid + BCE term.
__global__ __launch_bounds__(256) void fuse_row(
    const short* __restrict__ P, const float* __restrict__ bt,
    const float* __restrict__ bx, const float* __restrict__ Y,
    const float* __restrict__ truth, const float* __restrict__ Wy,
    const float* __restrict__ by, float* __restrict__ predOut,
    float* __restrict__ hidden, float* __restrict__ bce, int S) {
  const int b = blockIdx.x;
  const int tid = threadIdx.x;
  __shared__ int s_cnt;
  __shared__ int s_idx[8];
  __shared__ float s_val[8];
  __shared__ float s_red[4];
  if (tid == 0) s_cnt = 0;

  const int c = tid * 4;
  float s0 = 0.f, s1 = 0.f, s2 = 0.f, s3 = 0.f;
  for (int z = 0; z < S; ++z) {
    const short* Pr = P + ((long long)z * B_DIM + b) * H_DIM + c;
    uint2 u = *(const uint2*)Pr;
    s0 += bf2f((unsigned short)(u.x & 0xffff));
    s1 += bf2f((unsigned short)(u.x >> 16));
    s2 += bf2f((unsigned short)(u.y & 0xffff));
    s3 += bf2f((unsigned short)(u.y >> 16));
  }
  float4 bt4 = *(const float4*)(bt + c);
  float4 bx4 = *(const float4*)(bx + c);
  float h0 = tanhf(s0 + bt4.x + bx4.x);
  float h1 = tanhf(s1 + bt4.y + bx4.y);
  float h2 = tanhf(s2 + bt4.z + bx4.z);
  float h3 = tanhf(s3 + bt4.w + bx4.w);
  float* Hr = hidden + (long long)b * H_DIM + c;  // base unaligned -> scalar
  Hr[0] = h0; Hr[1] = h1; Hr[2] = h2; Hr[3] = h3;

  __syncthreads();  // covers s_cnt init
  const float4* Yr = (const float4*)(Y + (long long)b * NQ_DIM);
#pragma unroll
  for (int hh = 0; hh < NQ_DIM / 4 / 256; ++hh) {
    int j = tid + hh * 256;
    float4 v = Yr[j];
    if (v.x != 0.0f) { int p = atomicAdd(&s_cnt, 1); if (p < 8) { s_idx[p] = 4 * j;     s_val[p] = v.x; } }
    if (v.y != 0.0f) { int p = atomicAdd(&s_cnt, 1); if (p < 8) { s_idx[p] = 4 * j + 1; s_val[p] = v.y; } }
    if (v.z != 0.0f) { int p = atomicAdd(&s_cnt, 1); if (p < 8) { s_idx[p] = 4 * j + 2; s_val[p] = v.z; } }
    if (v.w != 0.0f) { int p = atomicAdd(&s_cnt, 1); if (p < 8) { s_idx[p] = 4 * j + 3; s_val[p] = v.w; } }
  }
  __syncthreads();
  int cnt = s_cnt < 8 ? s_cnt : 8;
  float predv = 0.0f;
  for (int it = 0; it < cnt; ++it) {
    int q = s_idx[it];
    float4 w = *(const float4*)(Wy + (long long)q * H_DIM + c);
    float part = h0 * w.x + h1 * w.y + h2 * w.z + h3 * w.w;
#pragma unroll
    for (int off = 32; off > 0; off >>= 1) part += __shfl_down(part, off, 64);
    if ((tid & 63) == 0) s_red[tid >> 6] = part;
    __syncthreads();
    if (tid == 0) {
      float z = s_red[0] + s_red[1] + s_red[2] + s_red[3] + by[q];
      float p = 1.0f / (1.0f + expf(-z));
      predv += s_val[it] * p;
    }
    __syncthreads();
  }
  if (tid == 0) {
    predOut[b] = predv;
    float t = truth[b];
    float lp = fmaxf(logf(predv), -100.0f);
    float l1p = fmaxf(log1pf(-predv), -100.0f);
    bce[b] = -(t * lp + (1.0f - t) * l1p);
  }
}

__global__ __launch_bounds__(256) void reduce_err(
    const float* __restrict__ bce, float* __restrict__ errOut) {
  float s = 0.0f;
  for (int i = threadIdx.x; i < B_DIM; i += 256) s += bce[i];
#pragma unroll
  for (int off = 32; off > 0; off >>= 1) s += __shfl_down(s, off, 64);
  __shared__ float red[4];
  if ((threadIdx.x & 63) == 0) red[threadIdx.x >> 6] = s;
  __syncthreads();
  if (threadIdx.x == 0) errOut[0] = red[0] + red[1] + red[2] + red[3];
}

extern "C" void kernel_launch(void* const* d_in, const int* in_sizes, int n_in,
                              void* d_out, int out_size, void* d_ws, size_t ws_size,
                              hipStream_t stream) {
  (void)in_sizes; (void)n_in; (void)out_size;
  const float* state  = (const float*)d_in[0];
  const float* inputX = (const float*)d_in[1];
  const float* inputY = (const float*)d_in[2];
  const float* truth  = (const float*)d_in[3];
  const float* W_t    = (const float*)d_in[4];
  const float* b_t    = (const float*)d_in[5];
  const float* W_x    = (const float*)d_in[6];
  const float* b_x    = (const float*)d_in[7];
  const float* W_y    = (const float*)d_in[8];
  const float* b_y    = (const float*)d_in[9];

  const size_t WC_B = (size_t)H_DIM * K_DIM * 2;   // 10.5 MB
  const size_t PART = (size_t)B_DIM * H_DIM * 2;   // 8.4 MB per split (bf16)

  int S = 1;
  if (ws_size >= WC_B + 4 * PART + 16384) S = 4;
  else if (ws_size >= WC_B + 2 * PART + 16384) S = 2;

  short* Wc = (short*)d_ws;
  short* P  = (short*)((char*)d_ws + WC_B);
  float* bce = (float*)((char*)d_ws + WC_B + (size_t)S * PART);

  float* predOut = (float*)d_out;             // [0 .. 4095]
  float* errOut  = predOut + B_DIM;           // [4096]
  float* hidden  = predOut + B_DIM + 1;       // [4097 ..]

  cast_w<<<(H_DIM / 128) * NKT, 256, 0, stream>>>(W_t, W_x, Wc);

  gemm_f32a<<<256 * S, 256, 0, stream>>>(state, inputX, Wc, P, NKT / S);

  fuse_row<<<B_DIM, 256, 0, stream>>>(P, b_t, b_x, inputY, truth, W_y, b_y,
                                      predOut, hidden, bce, S);
  reduce_err<<<1, 256, 0, stream>>>(bce, errOut);
}

// Round 11
// 92.190 us; speedup vs baseline: 1.2380x; 1.2067x over previous
//
#include <hip/hip_runtime.h>
#include <stdint.h>
#include <math.h>

#define B_DIM 4096
#define H_DIM 1024
#define NI_DIM 4096
#define NQ_DIM 2048
#define K_DIM 5120   // H + NI
#define NKT 160      // K_DIM / 32

typedef __attribute__((ext_vector_type(8))) short short8;
typedef __attribute__((ext_vector_type(4))) float f32x4;

__device__ __forceinline__ unsigned short f2bf(float f) {
  unsigned u = __float_as_uint(f);
  u += 0x7FFFu + ((u >> 16) & 1u);  // round-to-nearest-even
  return (unsigned short)(u >> 16);
}
__device__ __forceinline__ float bf2f(unsigned short s) {
  return __uint_as_float(((unsigned)s) << 16);
}
__device__ __forceinline__ unsigned pkbf(float a, float b) {
  unsigned r;
  asm("v_cvt_pk_bf16_f32 %0, %1, %2" : "=v"(r) : "v"(a), "v"(b));
  return r;
}

__device__ __forceinline__ void gload_lds16(const void* g, void* l) {
  __builtin_amdgcn_global_load_lds(
      (__attribute__((address_space(1))) void*)(uintptr_t)g,
      (__attribute__((address_space(3))) void*)l, 16, 0, 0);
}

// fp32 -> bf16 cast into staged-tile layout (proven R8 version, ~47us).
// Block = (rowTile, ktb4): 128 rows x 128 fp32 cols = 4 consecutive kt-tiles.
__global__ __launch_bounds__(256) void cast_v4(
    const float* __restrict__ X0, const float* __restrict__ X1,
    const float* __restrict__ W0, const float* __restrict__ W1,
    short* __restrict__ Xc, short* __restrict__ Wc) {
  __shared__ __align__(16) short lds[16384];  // 2048 chunks x 8 shorts
  int bt = blockIdx.x;
  const float *s0, *s1;
  short* dst;
  if (bt < (B_DIM / 128) * (NKT / 4)) { s0 = X0; s1 = X1; dst = Xc; }
  else { bt -= (B_DIM / 128) * (NKT / 4); s0 = W0; s1 = W1; dst = Wc; }
  const int rowTile = bt / (NKT / 4);
  const int K0 = (bt % (NKT / 4)) * 4;       // first kt of this block
  const float* src;
  int cols, colBase;
  if (K0 < 32) { src = s0; cols = 1024; colBase = K0 * 32; }
  else         { src = s1; cols = 4096; colBase = (K0 - 32) * 32; }
  const int tid = threadIdx.x;
  const int kc = tid & 31;      // float4 col chunk within 128 cols
  const int r0 = tid >> 5;      // starting row (8 rows per pass)
#pragma unroll
  for (int i = 0; i < 16; ++i) {
    int r = r0 + i * 8;
    float4 v = *(const float4*)(src +
        (long long)(rowTile * 128 + r) * cols + colBase + kc * 4);
    uint2 o;
    o.x = pkbf(v.x, v.y);
    o.y = pkbf(v.z, v.w);
    int l = (kc >> 1) * 128 + r;          // logical chunk (s16*128 + r)
    int p = l ^ ((l >> 7) & 7);           // physical (bank-spread)
    *(uint2*)(&lds[p * 8 + (kc & 1) * 4]) = o;
  }
  __syncthreads();
  short* dbase = dst + ((long long)rowTile * NKT + K0) * 4096;
#pragma unroll
  for (int i = 0; i < 8; ++i) {
    int c = tid + i * 256;
    int p = c ^ ((c >> 7) & 7);
    *(short8*)(dbase + c * 8) = *(const short8*)(&lds[p * 8]);
  }
}

// LDS byte-swizzle for the epilogue transpose buffer [col][row] bf16.
__device__ __forceinline__ int ep_swz(int col, int rw) {
  int byte = col * 512 + rw * 2;           // [col 0..255][row 0..255]
  byte ^= ((col ^ (col >> 3)) & 7) << 4;   // spread banks, keeps 8B align
  return byte;
}

// 256x256-tile split-K GEMM, BK=64, 512 threads, 8 waves (2M x 4N, wave
// tile 128x64, acc[8][4]). Same staged-tile inputs and conflict-free
// [slot][row][8] LDS pattern as the proven 128^2 kernel; LDS bytes/FLOP
// cut 25% (reads) / 50% (staging writes) -- the 128^2 kernel was
// LDS-BW-bound at ~73% busy. Dbuf 2x64KB = 128KB, 1 block/CU.
// Prefetch issued a full tile-phase (~3000 cyc >> 900 HBM) before the
// __syncthreads drain, so the simple 2-phase loop stays latency-clean.
__global__ __launch_bounds__(512, 2) void gemm_256(
    const short* __restrict__ Xc, const short* __restrict__ Wc,
    short* __restrict__ P, int ntile) {   // ntile = 80/S K-tiles of 64
  __shared__ __align__(16) short SH[65536];  // [slot][A 4x4096 | B 4x4096]
  const int tid = threadIdx.x;
  const int lane = tid & 63;
  const int wid = tid >> 6;            // 0..7
  const int wr = wid >> 2, wc = wid & 3;
  const int fr = lane & 15, fq = lane >> 4;

  const int nwg = gridDim.x;           // 64*S, divisible by 8
  const int orig = blockIdx.x;
  const int cpx = nwg >> 3;
  const int swz = (orig & 7) * cpx + (orig >> 3);
  const int bz = swz >> 6;             // split index
  const int bm = (swz >> 2) & 15;      // 256-row tile
  const int bn = swz & 3;              // 256-col tile
  const int kt0 = bz * (2 * ntile);    // first 32-k subtile of this split

  // global subtile base pointers (each subtile = 4096 shorts, contiguous)
  const short* gA0 = Xc + ((long long)((bm * 2 + 0) * NKT + kt0) << 12);
  const short* gA2 = Xc + ((long long)((bm * 2 + 1) * NKT + kt0) << 12);
  const short* gB0 = Wc + ((long long)((bn * 2 + 0) * NKT + kt0) << 12);
  const short* gB2 = Wc + ((long long)((bn * 2 + 1) * NKT + kt0) << 12);

  f32x4 acc[8][4] = {};

  const int t8 = tid * 8;

  // prologue: stage tile 0 into slot 0
  {
    gload_lds16(gA0 + t8, &SH[t8]);
    gload_lds16(gA0 + 4096 + t8, &SH[4096 + t8]);
    gload_lds16(gA2 + t8, &SH[8192 + t8]);
    gload_lds16(gA2 + 4096 + t8, &SH[12288 + t8]);
    gload_lds16(gB0 + t8, &SH[16384 + t8]);
    gload_lds16(gB0 + 4096 + t8, &SH[20480 + t8]);
    gload_lds16(gB2 + t8, &SH[24576 + t8]);
    gload_lds16(gB2 + 4096 + t8, &SH[28672 + t8]);
  }
  __syncthreads();

  int cur = 0;
  for (int t = 0; t < ntile; ++t) {
    if (t + 1 < ntile) {  // stage tile t+1 into the other slot (issue early)
      long long off = (long long)(t + 1) * 8192 + t8;
      short* L = &SH[(cur ^ 1) * 32768];
      gload_lds16(gA0 + off, L + t8);
      gload_lds16(gA0 + 4096 + off, L + 4096 + t8);
      gload_lds16(gA2 + off, L + 8192 + t8);
      gload_lds16(gA2 + 4096 + off, L + 12288 + t8);
      gload_lds16(gB0 + off, L + 16384 + t8);
      gload_lds16(gB0 + 4096 + off, L + 20480 + t8);
      gload_lds16(gB2 + off, L + 24576 + t8);
      gload_lds16(gB2 + 4096 + off, L + 28672 + t8);
    }
    const short* aS = &SH[cur * 32768] + wr * 8192;           // h = wr
    const short* bS = &SH[cur * 32768 + 16384] + (wc >> 1) * 8192;
    const int brow = (wc & 1) * 64;
#pragma unroll
    for (int ks = 0; ks < 2; ++ks) {
      short8 av[8], bv[4];
#pragma unroll
      for (int mi = 0; mi < 8; ++mi)
        av[mi] = *(const short8*)(aS + ks * 4096 +
                                  (fq * 128 + mi * 16 + fr) * 8);
#pragma unroll
      for (int ni = 0; ni < 4; ++ni)
        bv[ni] = *(const short8*)(bS + ks * 4096 +
                                  (fq * 128 + brow + ni * 16 + fr) * 8);
#pragma unroll
      for (int mi = 0; mi < 8; ++mi)
#pragma unroll
        for (int ni = 0; ni < 4; ++ni)
          acc[mi][ni] = __builtin_amdgcn_mfma_f32_16x16x32_bf16(
              av[mi], bv[ni], acc[mi][ni], 0, 0, 0);
    }
    __syncthreads();
    cur ^= 1;
  }

  // ---- epilogue: bf16 transpose through the full 128KB LDS ----
  // phase 1: lane writes 4 consecutive rows per fragment into [col][row].
#pragma unroll
  for (int ni = 0; ni < 4; ++ni) {
    int col = wc * 64 + ni * 16 + fr;
#pragma unroll
    for (int mi = 0; mi < 8; ++mi) {
      int rw = wr * 128 + mi * 16 + fq * 4;
      uint2 pk;
      pk.x = (unsigned)f2bf(acc[mi][ni][0]) |
             ((unsigned)f2bf(acc[mi][ni][1]) << 16);
      pk.y = (unsigned)f2bf(acc[mi][ni][2]) |
             ((unsigned)f2bf(acc[mi][ni][3]) << 16);
      *(uint2*)((char*)SH + ep_swz(col, rw)) = pk;
    }
  }
  __syncthreads();
  // phase 2: read row-major chunks (8 cols) back, short8 store to P.
  short* Pp = P + (long long)bz * B_DIM * H_DIM;
#pragma unroll
  for (int h = 0; h < 16; ++h) {
    int chunk = tid + h * 512;        // 8192 chunks = 256 rows x 32 colblocks
    int rr = chunk >> 5;
    int j = chunk & 31;
    short8 o;
#pragma unroll
    for (int k = 0; k < 8; ++k) {
      o[k] = *(const short*)((char*)SH + ep_swz(j * 8 + k, rr));
    }
    *(short8*)(Pp + (long long)(bm * 256 + rr) * H_DIM + bn * 256 + j * 8) = o;
  }
}

// Fused: per-row split-K reduce + bias + tanh + hidden write + one-hot
// select + Wy dot + sigmoid + BCE term.
__global__ __launch_bounds__(256) void fuse_row(
    const short* __restrict__ P, const float* __restrict__ bt,
    const float* __restrict__ bx, const float* __restrict__ Y,
    const float* __restrict__ truth, const float* __restrict__ Wy,
    const float* __restrict__ by, float* __restrict__ predOut,
    float* __restrict__ hidden, float* __restrict__ bce, int S) {
  const int b = blockIdx.x;
  const int tid = threadIdx.x;
  __shared__ int s_cnt;
  __shared__ int s_idx[8];
  __shared__ float s_val[8];
  __shared__ float s_red[4];
  if (tid == 0) s_cnt = 0;

  const int c = tid * 4;
  float s0 = 0.f, s1 = 0.f, s2 = 0.f, s3 = 0.f;
  for (int z = 0; z < S; ++z) {
    const short* Pr = P + ((long long)z * B_DIM + b) * H_DIM + c;
    uint2 u = *(const uint2*)Pr;
    s0 += bf2f((unsigned short)(u.x & 0xffff));
    s1 += bf2f((unsigned short)(u.x >> 16));
    s2 += bf2f((unsigned short)(u.y & 0xffff));
    s3 += bf2f((unsigned short)(u.y >> 16));
  }
  float4 bt4 = *(const float4*)(bt + c);
  float4 bx4 = *(const float4*)(bx + c);
  float h0 = tanhf(s0 + bt4.x + bx4.x);
  float h1 = tanhf(s1 + bt4.y + bx4.y);
  float h2 = tanhf(s2 + bt4.z + bx4.z);
  float h3 = tanhf(s3 + bt4.w + bx4.w);
  float* Hr = hidden + (long long)b * H_DIM + c;  // base unaligned -> scalar
  Hr[0] = h0; Hr[1] = h1; Hr[2] = h2; Hr[3] = h3;

  __syncthreads();  // covers s_cnt init
  const float4* Yr = (const float4*)(Y + (long long)b * NQ_DIM);
#pragma unroll
  for (int hh = 0; hh < NQ_DIM / 4 / 256; ++hh) {
    int j = tid + hh * 256;
    float4 v = Yr[j];
    if (v.x != 0.0f) { int p = atomicAdd(&s_cnt, 1); if (p < 8) { s_idx[p] = 4 * j;     s_val[p] = v.x; } }
    if (v.y != 0.0f) { int p = atomicAdd(&s_cnt, 1); if (p < 8) { s_idx[p] = 4 * j + 1; s_val[p] = v.y; } }
    if (v.z != 0.0f) { int p = atomicAdd(&s_cnt, 1); if (p < 8) { s_idx[p] = 4 * j + 2; s_val[p] = v.z; } }
    if (v.w != 0.0f) { int p = atomicAdd(&s_cnt, 1); if (p < 8) { s_idx[p] = 4 * j + 3; s_val[p] = v.w; } }
  }
  __syncthreads();
  int cnt = s_cnt < 8 ? s_cnt : 8;
  float predv = 0.0f;
  for (int it = 0; it < cnt; ++it) {
    int q = s_idx[it];
    float4 w = *(const float4*)(Wy + (long long)q * H_DIM + c);
    float part = h0 * w.x + h1 * w.y + h2 * w.z + h3 * w.w;
#pragma unroll
    for (int off = 32; off > 0; off >>= 1) part += __shfl_down(part, off, 64);
    if ((tid & 63) == 0) s_red[tid >> 6] = part;
    __syncthreads();
    if (tid == 0) {
      float z = s_red[0] + s_red[1] + s_red[2] + s_red[3] + by[q];
      float p = 1.0f / (1.0f + expf(-z));
      predv += s_val[it] * p;
    }
    __syncthreads();
  }
  if (tid == 0) {
    predOut[b] = predv;
    float t = truth[b];
    float lp = fmaxf(logf(predv), -100.0f);
    float l1p = fmaxf(log1pf(-predv), -100.0f);
    bce[b] = -(t * lp + (1.0f - t) * l1p);
  }
}

__global__ __launch_bounds__(256) void reduce_err(
    const float* __restrict__ bce, float* __restrict__ errOut) {
  float s = 0.0f;
  for (int i = threadIdx.x; i < B_DIM; i += 256) s += bce[i];
#pragma unroll
  for (int off = 32; off > 0; off >>= 1) s += __shfl_down(s, off, 64);
  __shared__ float red[4];
  if ((threadIdx.x & 63) == 0) red[threadIdx.x >> 6] = s;
  __syncthreads();
  if (threadIdx.x == 0) errOut[0] = red[0] + red[1] + red[2] + red[3];
}

extern "C" void kernel_launch(void* const* d_in, const int* in_sizes, int n_in,
                              void* d_out, int out_size, void* d_ws, size_t ws_size,
                              hipStream_t stream) {
  (void)in_sizes; (void)n_in; (void)out_size;
  const float* state  = (const float*)d_in[0];
  const float* inputX = (const float*)d_in[1];
  const float* inputY = (const float*)d_in[2];
  const float* truth  = (const float*)d_in[3];
  const float* W_t    = (const float*)d_in[4];
  const float* b_t    = (const float*)d_in[5];
  const float* W_x    = (const float*)d_in[6];
  const float* b_x    = (const float*)d_in[7];
  const float* W_y    = (const float*)d_in[8];
  const float* b_y    = (const float*)d_in[9];

  const size_t XC_B = (size_t)B_DIM * K_DIM * 2;   // 41.9 MB
  const size_t WC_B = (size_t)H_DIM * K_DIM * 2;   // 10.5 MB
  const size_t PART = (size_t)B_DIM * H_DIM * 2;   // 8.4 MB per split (bf16)

  int S = 1;
  if (ws_size >= XC_B + WC_B + 4 * PART + 16384) S = 4;
  else if (ws_size >= XC_B + WC_B + 2 * PART + 16384) S = 2;

  short* Xc = (short*)d_ws;
  short* Wc = (short*)((char*)d_ws + XC_B);
  short* P  = (short*)((char*)d_ws + XC_B + WC_B);
  float* bce = (float*)((char*)d_ws + XC_B + WC_B + (size_t)S * PART);

  float* predOut = (float*)d_out;             // [0 .. 4095]
  float* errOut  = predOut + B_DIM;           // [4096]
  float* hidden  = predOut + B_DIM + 1;       // [4097 ..]

  cast_v4<<<(B_DIM / 128 + H_DIM / 128) * (NKT / 4), 256, 0, stream>>>(
      state, inputX, W_t, W_x, Xc, Wc);

  gemm_256<<<64 * S, 512, 0, stream>>>(Xc, Wc, P, 80 / S);

  fuse_row<<<B_DIM, 256, 0, stream>>>(P, b_t, b_x, inputY, truth, W_y, b_y,
                                      predOut, hidden, bce, S);
  reduce_err<<<1, 256, 0, stream>>>(bce, errOut);
}